// Round 1
// baseline (338.797 us; speedup 1.0000x reference)
//
#include <hip/hip_runtime.h>

// LocallyConnectedLayer MI355X — R3: latency/scatter attack.
//  - A path LDS-free: each lane gathers its own MFMA A-fragment runs into regs
//  - M-split (64 batch rows per block) -> 900 blocks, ~3 blocks/CU resident
//  - lane-cooperative weight loads: 9 lanes per (c,o) pair, contiguous 72B
//  - double-buffered B LDS, 1 barrier/chunk, prefetch overlaps MFMA
// out[b,o,i,j] = bias[o,i,j] + sum_{c,kh,kw} x[b,c,i+kh,j+kw]*W[c,o,i,j,kh,kw]

#define BDIM 256

typedef __bf16 bf16x8 __attribute__((ext_vector_type(8)));
typedef float f32x4 __attribute__((ext_vector_type(4)));
typedef unsigned long long u64;

__device__ __forceinline__ unsigned short f2bf(float f) {
  union { float f; unsigned u; } v; v.f = f;
  unsigned r = v.u + 0x7fffu + ((v.u >> 16) & 1u);  // RTNE
  return (unsigned short)(r >> 16);
}

__device__ __forceinline__ bf16x8 mk_af(u64 lo, u64 hi) {
  union { u64 q[2]; bf16x8 v; } u;
  u.q[0] = lo; u.q[1] = hi;
  return u.v;
}

// x:    [128,64,32,32]  strides(f32) b:65536 c:1024 h:32 w:1
// wgt:  [64(c),64(o),30,30,3,3]; (c,o) flattened stride 8100 f -> P*32400 B
// bias: [64,30,30]; out: [128,64,30,30] strides b:57600 o:900 ij:1

__global__ __launch_bounds__(256, 3) void lcl_kernel(
    const float* __restrict__ x, const float* __restrict__ wgt,
    const float* __restrict__ bias, float* __restrict__ out) {
  // 900 blocks -> XCD-contiguous bijective swizzle (900 = 4*113 + 4*112)
  int bid = blockIdx.x;
  int xcd = bid & 7, sg = bid >> 3;
  int wg = (xcd < 4 ? xcd * 113 : 452 + (xcd - 4) * 112) + sg;
  int t    = wg >> 1;   // position pair id [0,450)
  int half = wg & 1;    // batch half (adjacent wg -> same XCD -> weight L2 hit)
  int i   = t / 15;
  int j0  = (t % 15) * 2;        // even
  int ij0 = i * 30 + j0;         // even

  // B LDS: [buf:2][dj:2][o:64][104 u16]  (104: 16B-aligned rows, proven stride)
  __shared__ __align__(16) unsigned short Bt[2 * 2 * 64 * 104];  // 53248 B

  const int tid  = threadIdx.x;
  const int wave = tid >> 6;
  const int lane = tid & 63;
  const int lrow = lane & 15;
  const int q    = lane >> 4;

  // zero LDS once (pad slots must be 0: A pad is 0, avoid 0*NaN)
  {
    u64* zp = (u64*)Bt;
#pragma unroll
    for (int k = 0; k < 26; ++k) zp[tid + k * 256] = 0ull;
  }

  // ---- per-lane x-run pointers: b fixed per lane, 6 runs g = s*8+q*2+tt
  const int b_x = half * 64 + wave * 16 + lrow;
  const float* xp[3][2];
#pragma unroll
  for (int s = 0; s < 3; ++s)
#pragma unroll
    for (int tt = 0; tt < 2; ++tt) {
      int g  = s * 8 + q * 2 + tt;
      int cc = g / 3, kh = g % 3;
      xp[s][tt] = x + b_x * 65536 + cc * 1024 + (i + kh) * 32 + j0;
    }

  // ---- B coop params: 9 lanes per (c,o) pair; pair P = pass*28 + U
  int p9 = lane / 9;             // 0..7 (lane63 -> dup of next slot, benign)
  int e9 = lane - p9 * 9;        // 0..8 -> floats f0=2e,f1=2e+1 of pair's 18
  int U  = wave * 7 + p9;        // 0..28
  const char* wbase = (const char*)wgt + (size_t)U * 32400 +
                      (size_t)(ij0 * 9 + e9 * 2) * 4;
  int f0 = 2 * e9, f1 = f0 + 1;
  int r0 = f0 % 9, r1 = f1 % 9;
  int sl0 = (f0 / 9) * 6656 + (r0 / 3) * 4 + (r0 % 3);  // dj*64*104 + kh*4 + kw
  int sl1 = (f1 / 9) * 6656 + (r1 / 3) * 4 + (r1 % 3);

  float2 av[3][2][2];   // x prefetch: 6 runs x 16B
  float2 wv[19];        // weight prefetch: 18 full passes + 1 predicated

#define LOAD_X(C0)                                                        \
  _Pragma("unroll") for (int s = 0; s < 3; ++s)                           \
  _Pragma("unroll") for (int tt = 0; tt < 2; ++tt) {                      \
    const float2* xq = (const float2*)(xp[s][tt] + (C0) * 1024);          \
    av[s][tt][0] = xq[0];                                                 \
    av[s][tt][1] = xq[1];                                                 \
  }

#define LOAD_W(C0)                                                        \
  {                                                                       \
    const char* wb = wbase + (size_t)(C0) * 2073600;                      \
    _Pragma("unroll") for (int ps = 0; ps < 18; ++ps)                     \
      wv[ps] = *(const float2*)(wb + ps * 907200);                        \
    if (U < 8) wv[18] = *(const float2*)(wb + 18 * 907200);               \
    else       wv[18] = float2{0.f, 0.f};                                 \
  }

  f32x4 acc[2][4];
#pragma unroll
  for (int a = 0; a < 2; ++a)
#pragma unroll
    for (int n = 0; n < 4; ++n) acc[a][n] = f32x4{0.f, 0.f, 0.f, 0.f};

  LOAD_X(0)
  LOAD_W(0)

  for (int chunk = 0; chunk < 8; ++chunk) {
    unsigned short* B = Bt + (chunk & 1) * 13312;

    // ---- write B slab from prefetched regs (fills Bt[cur]; prev chunk read
    //      the other buffer, and the barrier below orders reuse)
#pragma unroll
    for (int ps = 0; ps < 19; ++ps) {
      if (ps < 18 || U < 8) {            // pass 18 covers P=504..511 only
        int P  = ps * 28 + U;
        int cc = P >> 6, o = P & 63;
        int sb = cc * 12 + o * 104;
        B[sb + sl0] = f2bf(wv[ps].x);
        B[sb + sl1] = f2bf(wv[ps].y);
      }
    }

    // ---- convert own x runs to packed bf16
    u64 rb[3][2];
#pragma unroll
    for (int s = 0; s < 3; ++s)
#pragma unroll
      for (int tt = 0; tt < 2; ++tt) {
        unsigned short h0 = f2bf(av[s][tt][0].x);
        unsigned short h1 = f2bf(av[s][tt][0].y);
        unsigned short h2 = f2bf(av[s][tt][1].x);
        unsigned short h3 = f2bf(av[s][tt][1].y);
        rb[s][tt] = (u64)h0 | ((u64)h1 << 16) | ((u64)h2 << 32) |
                    ((u64)h3 << 48);
      }

    __syncthreads();

    // ---- issue next chunk's globals; latency hides under MFMA phase
    if (chunk < 7) {
      LOAD_X((chunk + 1) * 8)
      LOAD_W((chunk + 1) * 8)
    }

    // ---- MFMA phase (A from regs, B from LDS)
#pragma unroll
    for (int s = 0; s < 3; ++s) {
      bf16x8 bfr[2][4];
#pragma unroll
      for (int jj = 0; jj < 2; ++jj)
#pragma unroll
        for (int nt = 0; nt < 4; ++nt)
          bfr[jj][nt] = *reinterpret_cast<const bf16x8*>(
              &B[jj * 6656 + (nt * 16 + lrow) * 104 + s * 32 + q * 8]);
#pragma unroll
      for (int jj = 0; jj < 2; ++jj) {
        u64 lo = (rb[s][0] >> (jj * 16)) & 0x0000FFFFFFFFFFFFull;
        u64 hi = (rb[s][1] >> (jj * 16)) & 0x0000FFFFFFFFFFFFull;
        bf16x8 af = mk_af(lo, hi);
#pragma unroll
        for (int nt = 0; nt < 4; ++nt)
          acc[jj][nt] = __builtin_amdgcn_mfma_f32_16x16x32_bf16(
              af, bfr[jj][nt], acc[jj][nt], 0, 0, 0);
      }
    }
  }

  // ---- epilogue: D[row=q*4+r][col=lrow]; row->b, col->o; float2 over j0,j0+1
  const int b_out = half * 64 + wave * 16 + q * 4;
#pragma unroll
  for (int nt = 0; nt < 4; ++nt) {
    int o = nt * 16 + lrow;
    float2 bv = *(const float2*)(bias + o * 900 + ij0);
#pragma unroll
    for (int r = 0; r < 4; ++r) {
      int b = b_out + r;
      float2 res;
      res.x = acc[0][nt][r] + bv.x;
      res.y = acc[1][nt][r] + bv.y;
      *(float2*)(out + b * 57600 + o * 900 + ij0) = res;
    }
  }
}

extern "C" void kernel_launch(void* const* d_in, const int* in_sizes, int n_in,
                              void* d_out, int out_size, void* d_ws,
                              size_t ws_size, hipStream_t stream) {
  const float* x    = (const float*)d_in[0];
  const float* wgt  = (const float*)d_in[1];
  const float* bias = (const float*)d_in[2];
  float* out        = (float*)d_out;
  lcl_kernel<<<dim3(900), dim3(256), 0, stream>>>(x, wgt, bias, out);
}

// Round 2
// 314.143 us; speedup vs baseline: 1.0785x; 1.0785x over previous
//
#include <hip/hip_runtime.h>

// LocallyConnectedLayer MI355X — R4: request-count attack.
//  - 450 blocks, M=128 (minimal weight traffic: each weight byte gathered once)
//  - A-path in registers (no Aslab), double-buffered B LDS, 1 barrier/chunk
//  - x gather: unaligned dwordx4 (16B/request, was 2x float2)
//  - weight gather: 5x dwordx4 per 72B pair-run (was 9x float2)
// out[b,o,i,j] = bias[o,i,j] + sum_{c,kh,kw} x[b,c,i+kh,j+kw]*W[c,o,i,j,kh,kw]

typedef __bf16 bf16x8 __attribute__((ext_vector_type(8)));
typedef float f32x4 __attribute__((ext_vector_type(4)));
typedef unsigned long long u64;
typedef unsigned int u32t;
typedef unsigned short u16t;

struct __attribute__((packed, aligned(8))) uf4 { f32x4 v; };  // 8B-aligned 16B load

__device__ __forceinline__ u16t f2bf(float f) {
  union { float f; u32t u; } v; v.f = f;
  u32t r = v.u + 0x7fffu + ((v.u >> 16) & 1u);  // RTNE
  return (u16t)(r >> 16);
}
__device__ __forceinline__ u32t pk2(float a, float b) {
  return (u32t)f2bf(a) | ((u32t)f2bf(b) << 16);
}
__device__ __forceinline__ bf16x8 mk_af(u64 lo, u64 hi) {
  union { u64 q[2]; bf16x8 v; } u;
  u.q[0] = lo; u.q[1] = hi;
  return u.v;
}

// x:    [128,64,32,32]  strides(f32) b:65536 c:1024 h:32 w:1
// wgt:  [64(c),64(o),30,30,3,3]; pair P=(c,o) run of 18 floats at P*8100+ij0*9
// bias: [64,30,30]; out: [128,64,30,30] strides b:57600 o:900 ij:1

__global__ __launch_bounds__(256, 2) void lcl_kernel(
    const float* __restrict__ x, const float* __restrict__ wgt,
    const float* __restrict__ bias, float* __restrict__ out) {
  // XCD swizzle: contiguous tile ranges per XCD (450 = 2*57 + 6*56)
  int blk = blockIdx.x;
  int xcd = blk & 7, sg = blk >> 3;
  int t = xcd * 56 + (xcd < 2 ? xcd : 2) + sg;  // bijective on [0,450)
  int i = t / 15;
  int j0 = (t % 15) * 2;      // even
  int ij0 = i * 30 + j0;      // even

  // B LDS: [buf:2][dj:2][o:64][104 u16] (k' = (cc*3+kh)*4 + kw, pads zero)
  __shared__ __align__(16) u16t Bt[2 * 2 * 64 * 104];  // 53248 B

  const int tid  = threadIdx.x;
  const int wave = tid >> 6;
  const int lane = tid & 63;
  const int lrow = lane & 15;
  const int q    = lane >> 4;

  // zero LDS once (pad slots must stay 0: they multiply A's garbage lane-u16)
  {
    u64* zp = (u64*)Bt;
#pragma unroll
    for (int k = 0; k < 26; ++k) zp[tid + k * 256] = 0ull;
  }

  // ---- x run offsets per (s,tt): g = s*8 + q*2 + tt -> (cc,kh)
  int xoffF[3][2];
#pragma unroll
  for (int s = 0; s < 3; ++s)
#pragma unroll
    for (int tt = 0; tt < 2; ++tt) {
      int g = s * 8 + q * 2 + tt, cc = g / 3, kh = g - cc * 3;
      xoffF[s][tt] = cc * 1024 + kh * 32;
    }
  const float* xb0 = x + (wave * 32 + lrow) * 65536 + i * 32 + j0;  // mt=0
  const float* xb1 = xb0 + 16 * 65536;                               // mt=1

  // ---- weight bases: thread owns pairs (tid, tid+256): same o, ccl = wave(+4)
  const int o_w = tid & 63;
  const float* wb0 = wgt + (size_t)wave * 518400 + o_w * 8100 + ij0 * 9;
  const float* wb1 = wb0 + (size_t)4 * 518400;

  f32x4 av[2][3][2];  // x prefetch: 12 x 16B
  f32x4 wv[2][5];     // weight prefetch: 2 pairs x 5 segs (segs at 0,16,32,48,56B)

#define LOAD_CHUNK(C0)                                                        \
  {                                                                           \
    const float* xc0 = xb0 + (C0) * 1024;                                     \
    const float* xc1 = xb1 + (C0) * 1024;                                     \
    _Pragma("unroll") for (int s = 0; s < 3; ++s)                             \
    _Pragma("unroll") for (int tt = 0; tt < 2; ++tt) {                        \
      av[0][s][tt] = ((const uf4*)(xc0 + xoffF[s][tt]))->v;                   \
      av[1][s][tt] = ((const uf4*)(xc1 + xoffF[s][tt]))->v;                   \
    }                                                                         \
    const float* w0 = wb0 + (size_t)(C0) * 518400;                            \
    const float* w1 = wb1 + (size_t)(C0) * 518400;                            \
    _Pragma("unroll") for (int e = 0; e < 4; ++e) {                           \
      wv[0][e] = ((const uf4*)(w0 + e * 4))->v;                               \
      wv[1][e] = ((const uf4*)(w1 + e * 4))->v;                               \
    }                                                                         \
    wv[0][4] = ((const uf4*)(w0 + 14))->v;                                    \
    wv[1][4] = ((const uf4*)(w1 + 14))->v;                                    \
  }

  f32x4 acc[2][2][4];
#pragma unroll
  for (int a = 0; a < 2; ++a)
#pragma unroll
    for (int b = 0; b < 2; ++b)
#pragma unroll
      for (int c = 0; c < 4; ++c) acc[a][b][c] = f32x4{0.f, 0.f, 0.f, 0.f};

  LOAD_CHUNK(0)

  for (int chunk = 0; chunk < 8; ++chunk) {
    u16t* B = Bt + (chunk & 1) * 13312;

    // ---- B slab write from prefetched regs (dbuf: other buffer being read
    //      was consumed before the previous barrier)
#pragma unroll
    for (int p = 0; p < 2; ++p) {
      int ccl = wave + 4 * p;
      u16t* Bp = B + o_w * 104 + ccl * 12;  // dj=0 column base
      // dj0: floats 0..8 = wv[p][0].xyzw wv[p][1].xyzw wv[p][2].x
      *(u32t*)&Bp[0] = pk2(wv[p][0][0], wv[p][0][1]);   // taps 0,1 -> slots 0,1
      Bp[2]  = f2bf(wv[p][0][2]);                        // tap 2 -> slot 2
      Bp[4]  = f2bf(wv[p][0][3]);                        // tap 3 -> slot 4
      Bp[5]  = f2bf(wv[p][1][0]);                        // tap 4 -> slot 5
      Bp[6]  = f2bf(wv[p][1][1]);                        // tap 5 -> slot 6
      *(u32t*)&Bp[8] = pk2(wv[p][1][2], wv[p][1][3]);    // taps 6,7 -> slots 8,9
      Bp[10] = f2bf(wv[p][2][0]);                        // tap 8 -> slot 10
      // dj1: floats 9..17 = wv[p][2].yzw wv[p][3].xyzw wv[p][4].zw
      u16t* Bq = Bp + 6656;
      *(u32t*)&Bq[0] = pk2(wv[p][2][1], wv[p][2][2]);
      Bq[2]  = f2bf(wv[p][2][3]);
      Bq[4]  = f2bf(wv[p][3][0]);
      Bq[5]  = f2bf(wv[p][3][1]);
      Bq[6]  = f2bf(wv[p][3][2]);
      *(u32t*)&Bq[8] = pk2(wv[p][3][3], wv[p][4][2]);
      Bq[10] = f2bf(wv[p][4][3]);
    }

    // ---- convert own x runs to packed bf16 (4 taps j0..j0+3 per run)
    u64 rb[2][3][2];
#pragma unroll
    for (int mt = 0; mt < 2; ++mt)
#pragma unroll
      for (int s = 0; s < 3; ++s)
#pragma unroll
        for (int tt = 0; tt < 2; ++tt) {
          const f32x4 vv = av[mt][s][tt];
          rb[mt][s][tt] =
              (u64)pk2(vv[0], vv[1]) | ((u64)pk2(vv[2], vv[3]) << 32);
        }

    __syncthreads();

    // ---- issue next chunk's globals; latency hides under MFMA phase
    if (chunk < 7) LOAD_CHUNK((chunk + 1) * 8)

    // ---- MFMA phase (A from regs, B from LDS)
#pragma unroll
    for (int s = 0; s < 3; ++s) {
      bf16x8 bfr[2][4];
#pragma unroll
      for (int jj = 0; jj < 2; ++jj)
#pragma unroll
        for (int nt = 0; nt < 4; ++nt)
          bfr[jj][nt] = *reinterpret_cast<const bf16x8*>(
              &B[jj * 6656 + (nt * 16 + lrow) * 104 + s * 32 + q * 8]);
#pragma unroll
      for (int mt = 0; mt < 2; ++mt)
#pragma unroll
        for (int jj = 0; jj < 2; ++jj) {
          // shift selects taps jj..jj+2; 4th u16 is garbage for jj=0 but B's
          // slot-3 pad is 0 -> product 0
          u64 lo = rb[mt][s][0] >> (jj * 16);
          u64 hi = rb[mt][s][1] >> (jj * 16);
          bf16x8 af = mk_af(lo, hi);
#pragma unroll
          for (int nt = 0; nt < 4; ++nt)
            acc[mt][jj][nt] = __builtin_amdgcn_mfma_f32_16x16x32_bf16(
                af, bfr[jj][nt], acc[mt][jj][nt], 0, 0, 0);
        }
    }
  }

  // ---- epilogue: D[row=q*4+r][col=lrow]; row->b, col->o; float2 over j0,j0+1
#pragma unroll
  for (int nt = 0; nt < 4; ++nt) {
    int o = nt * 16 + lrow;
    float2 bv = *(const float2*)(bias + o * 900 + ij0);
#pragma unroll
    for (int mt = 0; mt < 2; ++mt) {
#pragma unroll
      for (int r = 0; r < 4; ++r) {
        int b = wave * 32 + mt * 16 + q * 4 + r;
        float2 res;
        res.x = acc[mt][0][nt][r] + bv.x;
        res.y = acc[mt][1][nt][r] + bv.y;
        *(float2*)(out + b * 57600 + o * 900 + ij0) = res;
      }
    }
  }
}

extern "C" void kernel_launch(void* const* d_in, const int* in_sizes, int n_in,
                              void* d_out, int out_size, void* d_ws,
                              size_t ws_size, hipStream_t stream) {
  const float* x    = (const float*)d_in[0];
  const float* wgt  = (const float*)d_in[1];
  const float* bias = (const float*)d_in[2];
  float* out        = (float*)d_out;
  lcl_kernel<<<dim3(450), dim3(256), 0, stream>>>(x, wgt, bias, out);
}